// Round 8
// baseline (34.477 us; speedup 1.0000x reference)
//
#include <hip/hip_runtime.h>

#define FIN   1024
#define FOUT2 1024
#define NTASK 20
#define BSZ   256
#define HOFF  (256 * 512)        // h output elements before logits

// Round-7 skeleton (pinned W + folded tree, 31.6us) + two levers:
//  1) W loads issued BEFORE the ballot (addresses don't depend on the sample
//     list) -> 16 outstanding loads overlap the ballot barriers instead of
//     serializing after them.
//  2) slot-split 2 -> 4 (balanced ranges [slot*n/4,(slot+1)*n/4)): 5120 blocks,
//     per-block chain ~1.6 pairs; slots of a tile stay 64 apart in blockIdx
//     (0 mod 8) -> same XCD L2 serves W re-reads (W is L3-resident anyway).
// Per-sample math, fold order, and stores bit-identical to round 7.
__global__ __launch_bounds__(256, 2)
void cond_linear_kernel(const float* __restrict__ x,
                        const int* __restrict__ task_id,
                        const float* __restrict__ W,
                        float* __restrict__ out) {
    __shared__ int sh_ord[BSZ];
    __shared__ int wcnt[4];
    __shared__ int sh_n;

    const int tid  = threadIdx.x;
    const int lane = tid & 63;
    const int wv   = tid >> 6;
    const int bx   = blockIdx.x;
    const int t    = bx >> 8;             // 256 blocks per task
    const int rem  = bx & 255;
    const int tile = rem & 63;            // 64 tiles of 16 outputs
    const int slot = rem >> 6;            // 4 sample slots
    const int o0   = tile * 16 + wv * 4;  // this wave's 4 output rows

    // ---- issue this wave's 16 W loads FIRST (overlap ballot barriers) ----
    const float* Wt = W + (size_t)t * (FOUT2 * FIN);
    float4 wr[4][4];
    #pragma unroll
    for (int r = 0; r < 4; ++r) {
        const float4* wp = (const float4*)(Wt + (size_t)(o0 + r) * FIN);
        #pragma unroll
        for (int p = 0; p < 4; ++p)
            wr[r][p] = wp[p * 64 + lane];
    }

    // ---- stable per-task sample list (identical to prior passing rounds) ----
    const int my_task = task_id[tid];
    const bool match = (my_task == t);
    const unsigned long long m64 = __ballot(match);
    if (lane == 0) wcnt[wv] = __popcll(m64);
    __syncthreads();
    int base = 0;
    #pragma unroll
    for (int w = 0; w < 4; ++w)
        if (w < wv) base += wcnt[w];
    if (match) {
        const int pos = base + __popcll(m64 & ((1ull << lane) - 1ull));
        sh_ord[pos] = tid;
    }
    if (tid == 0) sh_n = wcnt[0] + wcnt[1] + wcnt[2] + wcnt[3];
    __syncthreads();
    const int n = sh_n;
    const int i0 = (slot * n) >> 2;       // balanced slot range
    const int i1 = ((slot + 1) * n) >> 2;
    if (i0 >= i1) return;

    // ---- PIN W in VGPRs (no remat possible) ----
    #pragma unroll
    for (int r = 0; r < 4; ++r)
        #pragma unroll
        for (int p = 0; p < 4; ++p)
            asm volatile("" : "+v"(wr[r][p].x), "+v"(wr[r][p].y),
                              "+v"(wr[r][p].z), "+v"(wr[r][p].w));

    // lane identity bits for the folded tree
    const bool hi32 = (lane & 32) != 0;
    const bool hi16 = (lane & 16) != 0;
    const bool hi8  = (lane & 8)  != 0;

    // ---- preload first sample pair ----
    int sa = sh_ord[i0];
    int sb = sh_ord[(i0 + 1 < i1) ? i0 + 1 : i1 - 1];
    float4 xa[4], xb[4];
    #pragma unroll
    for (int p = 0; p < 4; ++p)
        xa[p] = ((const float4*)(x + (size_t)sa * FIN))[p * 64 + lane];
    #pragma unroll
    for (int p = 0; p < 4; ++p)
        xb[p] = ((const float4*)(x + (size_t)sb * FIN))[p * 64 + lane];

    for (int i = i0; i < i1; i += 2) {
        // prefetch next pair (clamped; tail duplicates are benign)
        const int ina = (i + 2 < i1) ? i + 2 : i1 - 1;
        const int inb = (i + 3 < i1) ? i + 3 : i1 - 1;
        const int na_s = sh_ord[ina];
        const int nb_s = sh_ord[inb];
        float4 na[4], nb[4];
        #pragma unroll
        for (int p = 0; p < 4; ++p)
            na[p] = ((const float4*)(x + (size_t)na_s * FIN))[p * 64 + lane];
        #pragma unroll
        for (int p = 0; p < 4; ++p)
            nb[p] = ((const float4*)(x + (size_t)nb_s * FIN))[p * 64 + lane];

        float a0 = 0.f, a1 = 0.f, a2 = 0.f, a3 = 0.f;
        float b0 = 0.f, b1 = 0.f, b2 = 0.f, b3 = 0.f;
        #pragma unroll
        for (int p = 0; p < 4; ++p) {
            const float4 u = xa[p];
            const float4 v = xb[p];
            a0 += wr[0][p].x * u.x + wr[0][p].y * u.y + wr[0][p].z * u.z + wr[0][p].w * u.w;
            a1 += wr[1][p].x * u.x + wr[1][p].y * u.y + wr[1][p].z * u.z + wr[1][p].w * u.w;
            a2 += wr[2][p].x * u.x + wr[2][p].y * u.y + wr[2][p].z * u.z + wr[2][p].w * u.w;
            a3 += wr[3][p].x * u.x + wr[3][p].y * u.y + wr[3][p].z * u.z + wr[3][p].w * u.w;
            b0 += wr[0][p].x * v.x + wr[0][p].y * v.y + wr[0][p].z * v.z + wr[0][p].w * v.w;
            b1 += wr[1][p].x * v.x + wr[1][p].y * v.y + wr[1][p].z * v.z + wr[1][p].w * v.w;
            b2 += wr[2][p].x * v.x + wr[2][p].y * v.y + wr[2][p].z * v.z + wr[2][p].w * v.w;
            b3 += wr[3][p].x * v.x + wr[3][p].y * v.y + wr[3][p].z * v.z + wr[3][p].w * v.w;
        }

        // ---- folded reduction tree (bit-identical to full 32..1 butterfly) ----
        const float t0 = a0 + __shfl_xor(a0, 32, 64);
        const float t1 = a1 + __shfl_xor(a1, 32, 64);
        const float t2 = a2 + __shfl_xor(a2, 32, 64);
        const float t3 = a3 + __shfl_xor(a3, 32, 64);
        const float t4 = b0 + __shfl_xor(b0, 32, 64);
        const float t5 = b1 + __shfl_xor(b1, 32, 64);
        const float t6 = b2 + __shfl_xor(b2, 32, 64);
        const float t7 = b3 + __shfl_xor(b3, 32, 64);
        float w0 = hi32 ? t4 : t0;
        float w1 = hi32 ? t5 : t1;
        float w2 = hi32 ? t6 : t2;
        float w3 = hi32 ? t7 : t3;
        w0 += __shfl_xor(w0, 16, 64);
        w1 += __shfl_xor(w1, 16, 64);
        w2 += __shfl_xor(w2, 16, 64);
        w3 += __shfl_xor(w3, 16, 64);
        float u0 = hi16 ? w2 : w0;
        float u1 = hi16 ? w3 : w1;
        u0 += __shfl_xor(u0, 8, 64);
        u1 += __shfl_xor(u1, 8, 64);
        float z = hi8 ? u1 : u0;
        z += __shfl_xor(z, 4, 64);
        z += __shfl_xor(z, 2, 64);
        z += __shfl_xor(z, 1, 64);
        const float zp = __shfl_xor(z, 8, 64);   // partner row (r^1)

        const int r_id = (hi8 ? 1 : 0) + (hi16 ? 2 : 0);
        const int s_idx = hi32 ? sb : sa;
        if ((lane & 7) == 0) {
            out[HOFF + (size_t)s_idx * FOUT2 + o0 + r_id] = z;
            if (!hi8) {   // even row: h = (logit_even >= logit_odd)
                out[(size_t)s_idx * (FOUT2 / 2) + (o0 >> 1) + (hi16 ? 1 : 0)]
                    = (z >= zp) ? 1.0f : 0.0f;
            }
        }

        sa = na_s; sb = nb_s;
        #pragma unroll
        for (int p = 0; p < 4; ++p) { xa[p] = na[p]; xb[p] = nb[p]; }
    }
}

extern "C" void kernel_launch(void* const* d_in, const int* in_sizes, int n_in,
                              void* d_out, int out_size, void* d_ws, size_t ws_size,
                              hipStream_t stream) {
    const float* x       = (const float*)d_in[0];
    const int*   task_id = (const int*)d_in[1];
    const float* W       = (const float*)d_in[2];
    float*       out     = (float*)d_out;

    dim3 grid(NTASK * 64 * 4);
    dim3 block(BSZ);
    hipLaunchKernelGGL(cond_linear_kernel, grid, block, 0, stream,
                       x, task_id, W, out);
}

// Round 9
// 29.441 us; speedup vs baseline: 1.1711x; 1.1711x over previous
//
#include <hip/hip_runtime.h>

#define FIN   1024
#define FOUT2 1024
#define NTASK 20
#define NRG   256                 // row-groups of 4 output rows
#define NSLOT 2                   // sample slots (round-7 proven value)
#define NW    (NTASK * NRG * NSLOT)   // 10240 single-wave blocks
#define HOFF  (256 * 512)         // h output elements before logits

// Round-9: barrier-free single-wave blocks.
//  - Each 64-lane block redundantly builds the task's sample list: lane loads
//    4 task_ids (int4), 4x __ballot -> full 256-bit match mask, incremental
//    popcount rank -> per-wave LDS scatter (write->read within one wave needs
//    only lgkmcnt, NO __syncthreads). Zero barriers in the kernel.
//  - W loads issued first; with no barrier there is no vmcnt(0) drain - they
//    stay outstanding through list construction.
//  - XCD-chunk swizzle: orig=(bid&7)*(NW/8)+(bid>>3), task-major, slot fastest
//    -> each XCD's L2 serves ~2.5 tasks' W; slot pairs adjacent (L2 hits).
// Sample order, per-dot FMA order, fold tree, stores bit-identical to round 7.
__global__ __launch_bounds__(64, 2)
void cond_linear_kernel(const float* __restrict__ x,
                        const int* __restrict__ task_id,
                        const float* __restrict__ W,
                        float* __restrict__ out) {
    __shared__ int sh_ord[64];

    const int lane = threadIdx.x;          // block == one wave
    const int bid  = blockIdx.x;
    const int orig = (bid & 7) * (NW / 8) + (bid >> 3);   // XCD-chunk swizzle
    const int t    = orig >> 9;            // 512 blocks per task
    const int r2   = orig & 511;
    const int rg   = r2 >> 1;              // row-group (4 rows)
    const int slot = r2 & 1;
    const int o0   = rg * 4;               // this wave's 4 output rows

    // ---- issue the 16 W loads FIRST (no barrier anywhere -> no drain) ----
    const float* Wt = W + (size_t)t * (FOUT2 * FIN);
    float4 wr[4][4];
    #pragma unroll
    for (int r = 0; r < 4; ++r) {
        const float4* wp = (const float4*)(Wt + (size_t)(o0 + r) * FIN);
        #pragma unroll
        for (int p = 0; p < 4; ++p)
            wr[r][p] = wp[p * 64 + lane];
    }

    // ---- barrier-free sample list: ballot + rank + per-wave LDS scatter ----
    const int4 ids = ((const int4*)task_id)[lane];        // samples 4l..4l+3
    const unsigned long long m0 = __ballot(ids.x == t);
    const unsigned long long m1 = __ballot(ids.y == t);
    const unsigned long long m2 = __ballot(ids.z == t);
    const unsigned long long m3 = __ballot(ids.w == t);
    const unsigned long long below = (1ull << lane) - 1ull;
    int rank = __popcll(m0 & below) + __popcll(m1 & below)
             + __popcll(m2 & below) + __popcll(m3 & below);
    if (ids.x == t) sh_ord[rank] = 4 * lane + 0;
    rank += (int)((m0 >> lane) & 1);
    if (ids.y == t) sh_ord[rank] = 4 * lane + 1;
    rank += (int)((m1 >> lane) & 1);
    if (ids.z == t) sh_ord[rank] = 4 * lane + 2;
    rank += (int)((m2 >> lane) & 1);
    if (ids.w == t) sh_ord[rank] = 4 * lane + 3;

    const int n = __popcll(m0) + __popcll(m1) + __popcll(m2) + __popcll(m3);
    const int half = (n + 1) >> 1;
    const int i0 = slot ? half : 0;
    const int i1 = slot ? n    : half;
    if (i0 >= i1) return;

    // ---- PIN W in VGPRs (no remat possible) ----
    #pragma unroll
    for (int r = 0; r < 4; ++r)
        #pragma unroll
        for (int p = 0; p < 4; ++p)
            asm volatile("" : "+v"(wr[r][p].x), "+v"(wr[r][p].y),
                              "+v"(wr[r][p].z), "+v"(wr[r][p].w));

    // lane identity bits for the folded tree
    const bool hi32 = (lane & 32) != 0;
    const bool hi16 = (lane & 16) != 0;
    const bool hi8  = (lane & 8)  != 0;

    // ---- preload first sample pair ----
    int sa = sh_ord[i0];
    int sb = sh_ord[(i0 + 1 < i1) ? i0 + 1 : i1 - 1];
    float4 xa[4], xb[4];
    #pragma unroll
    for (int p = 0; p < 4; ++p)
        xa[p] = ((const float4*)(x + (size_t)sa * FIN))[p * 64 + lane];
    #pragma unroll
    for (int p = 0; p < 4; ++p)
        xb[p] = ((const float4*)(x + (size_t)sb * FIN))[p * 64 + lane];

    for (int i = i0; i < i1; i += 2) {
        // prefetch next pair (clamped; tail duplicates are benign)
        const int ina = (i + 2 < i1) ? i + 2 : i1 - 1;
        const int inb = (i + 3 < i1) ? i + 3 : i1 - 1;
        const int na_s = sh_ord[ina];
        const int nb_s = sh_ord[inb];
        float4 na[4], nb[4];
        #pragma unroll
        for (int p = 0; p < 4; ++p)
            na[p] = ((const float4*)(x + (size_t)na_s * FIN))[p * 64 + lane];
        #pragma unroll
        for (int p = 0; p < 4; ++p)
            nb[p] = ((const float4*)(x + (size_t)nb_s * FIN))[p * 64 + lane];

        float a0 = 0.f, a1 = 0.f, a2 = 0.f, a3 = 0.f;
        float b0 = 0.f, b1 = 0.f, b2 = 0.f, b3 = 0.f;
        #pragma unroll
        for (int p = 0; p < 4; ++p) {
            const float4 u = xa[p];
            const float4 v = xb[p];
            a0 += wr[0][p].x * u.x + wr[0][p].y * u.y + wr[0][p].z * u.z + wr[0][p].w * u.w;
            a1 += wr[1][p].x * u.x + wr[1][p].y * u.y + wr[1][p].z * u.z + wr[1][p].w * u.w;
            a2 += wr[2][p].x * u.x + wr[2][p].y * u.y + wr[2][p].z * u.z + wr[2][p].w * u.w;
            a3 += wr[3][p].x * u.x + wr[3][p].y * u.y + wr[3][p].z * u.z + wr[3][p].w * u.w;
            b0 += wr[0][p].x * v.x + wr[0][p].y * v.y + wr[0][p].z * v.z + wr[0][p].w * v.w;
            b1 += wr[1][p].x * v.x + wr[1][p].y * v.y + wr[1][p].z * v.z + wr[1][p].w * v.w;
            b2 += wr[2][p].x * v.x + wr[2][p].y * v.y + wr[2][p].z * v.z + wr[2][p].w * v.w;
            b3 += wr[3][p].x * v.x + wr[3][p].y * v.y + wr[3][p].z * v.z + wr[3][p].w * v.w;
        }

        // ---- folded reduction tree (bit-identical to full 32..1 butterfly) ----
        const float t0 = a0 + __shfl_xor(a0, 32, 64);
        const float t1 = a1 + __shfl_xor(a1, 32, 64);
        const float t2 = a2 + __shfl_xor(a2, 32, 64);
        const float t3 = a3 + __shfl_xor(a3, 32, 64);
        const float t4 = b0 + __shfl_xor(b0, 32, 64);
        const float t5 = b1 + __shfl_xor(b1, 32, 64);
        const float t6 = b2 + __shfl_xor(b2, 32, 64);
        const float t7 = b3 + __shfl_xor(b3, 32, 64);
        float w0 = hi32 ? t4 : t0;
        float w1 = hi32 ? t5 : t1;
        float w2 = hi32 ? t6 : t2;
        float w3 = hi32 ? t7 : t3;
        w0 += __shfl_xor(w0, 16, 64);
        w1 += __shfl_xor(w1, 16, 64);
        w2 += __shfl_xor(w2, 16, 64);
        w3 += __shfl_xor(w3, 16, 64);
        float u0 = hi16 ? w2 : w0;
        float u1 = hi16 ? w3 : w1;
        u0 += __shfl_xor(u0, 8, 64);
        u1 += __shfl_xor(u1, 8, 64);
        float z = hi8 ? u1 : u0;
        z += __shfl_xor(z, 4, 64);
        z += __shfl_xor(z, 2, 64);
        z += __shfl_xor(z, 1, 64);
        const float zp = __shfl_xor(z, 8, 64);   // partner row (r^1)

        const int r_id = (hi8 ? 1 : 0) + (hi16 ? 2 : 0);
        const int s_idx = hi32 ? sb : sa;
        if ((lane & 7) == 0) {
            out[HOFF + (size_t)s_idx * FOUT2 + o0 + r_id] = z;
            if (!hi8) {   // even row: h = (logit_even >= logit_odd)
                out[(size_t)s_idx * (FOUT2 / 2) + (o0 >> 1) + (hi16 ? 1 : 0)]
                    = (z >= zp) ? 1.0f : 0.0f;
            }
        }

        sa = na_s; sb = nb_s;
        #pragma unroll
        for (int p = 0; p < 4; ++p) { xa[p] = na[p]; xb[p] = nb[p]; }
    }
}

extern "C" void kernel_launch(void* const* d_in, const int* in_sizes, int n_in,
                              void* d_out, int out_size, void* d_ws, size_t ws_size,
                              hipStream_t stream) {
    const float* x       = (const float*)d_in[0];
    const int*   task_id = (const int*)d_in[1];
    const float* W       = (const float*)d_in[2];
    float*       out     = (float*)d_out;

    dim3 grid(NW);
    dim3 block(64);
    hipLaunchKernelGGL(cond_linear_kernel, grid, block, 0, stream,
                       x, task_id, W, out);
}